// Round 4
// baseline (1532.643 us; speedup 1.0000x reference)
//
#include <hip/hip_runtime.h>
#include <cmath>

// out = (log(|DCT2(x)| + 1e-13) - mean) / std,  x: [384][256][256] f32.
// CORRECTNESS CONTRACT (R1-R3 evidence): reference accumulates in f32;
// near-zero DCT coefficients are f32 rounding NOISE and log() demands we
// reproduce that noise ~exactly. Every output element must be a single
// sequential fmaf chain, i ascending (stage 1) / j ascending (stage 2),
// with the stage-1 result rounded to f32. NO MFMA, NO split accumulators.
//
// R8 (from R7 counters: VALUBusy 49%, VGPR_Count 40, occupancy 45%):
// R6/R7's basis stream used SMEM (s_load). SMEM returns are OUT-OF-ORDER ->
// compiler drains with lgkmcnt(0) before every FMA block; the load was
// issued only ~128cy earlier vs ~250cy scalar-L2 latency -> ~50% stall.
// Fix: NO SMEM in the loop. Basis rows are loaded as uniform-address
// VECTOR loads (global_load_dwordx4, 64 lanes same addr -> 1 L1 txn +
// broadcast). VMEM returns are IN-ORDER -> fine-grained vmcnt waits.
// True modulo-scheduled pipeline, NO register copies (copies defeated
// R7's depth): unroll-4 body, static buffers; X stream at distance 4
// (~1500cy wall slack > 900cy HBM miss), basis at distance 2 (~1000cy
// slack > 300cy L2). k1b/k2b derived from threadIdx (divergent to the
// compiler) so loads stay VMEM. ~120 VGPR -> 4 waves/SIMD honest.
// Numerics bit-identical chains to the R4-R7 passing kernels.

#define HN    256
#define NIMG  384

// ---- f32 basis: Tdf[i][k] = (float)( cos(pi*(2i+1)*k/512) * s(k) ) --------
__global__ void basis_init(float* __restrict__ Tdf) {
    int idx = blockIdx.x * 256 + threadIdx.x;   // 65536
    int i = idx >> 8, k = idx & 255;
    double c = cos(M_PI * (2.0 * i + 1.0) * (double)k / 512.0);
    double s = (k == 0) ? sqrt(1.0 / 256.0) : sqrt(2.0 / 256.0);
    Tdf[idx] = (float)(c * s);
}

// blockIdx swizzle: the 4 blocks of one image land on the same XCD
// (HW round-robins consecutive workgroups across the 8 XCDs).
// n in [0,1536): img = (n&7)*48 + (n>>5), kg = (n>>3)&3. Bijective.
__device__ __forceinline__ void decode_bx(int n, int& img, int& kg) {
    img = (n & 7) * 48 + (n >> 5);
    kg  = (n >> 3) & 3;
}

// 64 fmaf: acc[q].c += S[q] * V.c   (S broadcast VGPR per q, V float4/lane)
#define FMA16(S, V) \
    _Pragma("unroll") \
    for (int q = 0; q < 16; ++q) { \
        acc[q].x = fmaf((S)[q], (V).x, acc[q].x); \
        acc[q].y = fmaf((S)[q], (V).y, acc[q].y); \
        acc[q].z = fmaf((S)[q], (V).z, acc[q].z); \
        acc[q].w = fmaf((S)[q], (V).w, acc[q].w); \
    }

#define BLOAD(DST, P) \
    _Pragma("unroll") \
    for (int a = 0; a < 4; ++a) \
        *(float4*)&(DST)[4 * a] = *(const float4*)((P) + 4 * a);

// Modulo-scheduled main loop, rows ascending, no copies.
// vp: per-lane vector stream (float4, row stride HN), distance-4 prefetch.
// bp: uniform-address broadcast stream (16 f/row), distance-2 prefetch.
// Declares acc[16] (float4) and consumes rows 0..HN-1 exactly once, in order.
#define DCT_PIPELINE(vp, bp) \
    float4 acc[16]; \
    _Pragma("unroll") \
    for (int q = 0; q < 16; ++q) acc[q] = make_float4(0.f, 0.f, 0.f, 0.f); \
    float4 vbuf[4]; \
    float  bbuf[2][16]; \
    _Pragma("unroll") \
    for (int m = 0; m < 4; ++m) vbuf[m] = *(const float4*)((vp) + m * HN); \
    BLOAD(bbuf[0], (bp) + 0 * HN); \
    BLOAD(bbuf[1], (bp) + 1 * HN); \
    _Pragma("unroll 1") \
    for (int i = 0; i < HN - 4; i += 4) { \
        _Pragma("unroll") \
        for (int m = 0; m < 4; ++m) { \
            FMA16(bbuf[m & 1], vbuf[m]); \
            vbuf[m] = *(const float4*)((vp) + (m + 4) * HN); \
            BLOAD(bbuf[m & 1], (bp) + (m + 2) * HN); \
        } \
        (vp) += 4 * HN; (bp) += 4 * HN; \
    } \
    /* rows 252..255; bbuf[0]=row252, bbuf[1]=row253; bases at row 252 */ \
    FMA16(bbuf[0], vbuf[0]); \
    BLOAD(bbuf[0], (bp) + 2 * HN);   /* row 254 */ \
    FMA16(bbuf[1], vbuf[1]); \
    BLOAD(bbuf[1], (bp) + 3 * HN);   /* row 255 */ \
    FMA16(bbuf[0], vbuf[2]); \
    FMA16(bbuf[1], vbuf[3]);

// ======================= two-kernel LDS-free path ==========================
// Stage 1: T1t[img][j][k1] = sum_i Tdf[i][k1] * X[img][i][j]   (i ascending)
// Block = 4 waves; wave w owns k1 slab [k1b,k1b+16), lanes span j (4/lane).
// Vector: X row i (coalesced streaming). Broadcast: Tdf[i][k1b..+15].
__global__ __launch_bounds__(256, 4) void t1_kernel(
    const float* __restrict__ X, const float* __restrict__ Tdf,
    float* __restrict__ T1t)
{
    int img, kg; decode_bx(blockIdx.x, img, kg);
    const int wave = threadIdx.x >> 6;
    const int lane = threadIdx.x & 63;
    const int k1b  = kg * 64 + wave * 16;   // tid-derived: stays VMEM

    const float* __restrict__ vp = X + (size_t)img * (HN * HN) + 4 * lane;
    const float* __restrict__ bp = Tdf + k1b;

    DCT_PIPELINE(vp, bp)

    // transposed store: T1t[img][4*lane+r][k1b + 4a + 0..3]
    float* __restrict__ T1o =
        T1t + (size_t)img * (HN * HN) + (size_t)(4 * lane) * HN + k1b;
    const float* af = (const float*)acc;     // af[4*q + r]
    #pragma unroll
    for (int r = 0; r < 4; ++r)
        #pragma unroll
        for (int a = 0; a < 4; ++a) {
            float4 v = make_float4(af[4 * (4 * a + 0) + r],
                                   af[4 * (4 * a + 1) + r],
                                   af[4 * (4 * a + 2) + r],
                                   af[4 * (4 * a + 3) + r]);
            *(float4*)(T1o + r * HN + 4 * a) = v;
        }
}

// Stage 2: out[k1][k2] = sum_j T1t[j][k1] * Tdf[j][k2]   (j ascending) + epi
// Block = 4 waves; wave w owns k2 slab [k2b,k2b+16), lanes span k1 (4/lane).
// Vector: T1t row j (coalesced streaming). Broadcast: Tdf[j][k2b..+15].
__global__ __launch_bounds__(256, 4) void y_kernel(
    const float* __restrict__ T1t, const float* __restrict__ Tdf,
    const float* __restrict__ meanp, const float* __restrict__ stdp,
    float* __restrict__ out)
{
    int img, kg; decode_bx(blockIdx.x, img, kg);
    const int wave = threadIdx.x >> 6;
    const int lane = threadIdx.x & 63;
    const int k2b  = kg * 64 + wave * 16;   // tid-derived: stays VMEM

    const float* __restrict__ vp = T1t + (size_t)img * (HN * HN) + 4 * lane;
    const float* __restrict__ bp = Tdf + k2b;

    DCT_PIPELINE(vp, bp)

    // epilogue + transposed store: out[img][4*lane+r][k2b + 4a + 0..3]
    const float mean = meanp[0];
    const float stdv = stdp[0];
    float* __restrict__ O =
        out + (size_t)img * (HN * HN) + (size_t)(4 * lane) * HN + k2b;
    const float* af = (const float*)acc;     // af[4*q + r]
    #pragma unroll
    for (int r = 0; r < 4; ++r)
        #pragma unroll
        for (int a = 0; a < 4; ++a) {
            float4 v;
            v.x = (logf(fabsf(af[4 * (4 * a + 0) + r]) + 1e-13f) - mean) / stdv;
            v.y = (logf(fabsf(af[4 * (4 * a + 1) + r]) + 1e-13f) - mean) / stdv;
            v.z = (logf(fabsf(af[4 * (4 * a + 2) + r]) + 1e-13f) - mean) / stdv;
            v.w = (logf(fabsf(af[4 * (4 * a + 3) + r]) + 1e-13f) - mean) / stdv;
            *(float4*)(O + r * HN + 4 * a) = v;
        }
}

// ======================= fused fallback (R3, proven) =======================
#define SLAB 32
__global__ __launch_bounds__(256, 3) void dct2_f32(
    const float* __restrict__ X, const float* __restrict__ Tdf,
    const float* __restrict__ meanp, const float* __restrict__ stdp,
    float* __restrict__ out)
{
    __shared__ union SU {
        struct { float Xs[8][HN]; float CHc[8][SLAB]; } p1;
        float Bc[16][HN];
    } u;
    __shared__ float T1s[SLAB][HN + 1];

    const int t   = threadIdx.x;
    const int img = blockIdx.x >> 3;
    const int k0  = (blockIdx.x & 7) * SLAB;
    const float* __restrict__ Xi = X + (size_t)img * (HN * HN);
    const int ci = t & 7;
    const int ib = t >> 3;

    float acc[8][4];
    #pragma unroll
    for (int q = 0; q < 8; ++q)
        #pragma unroll
        for (int r = 0; r < 4; ++r) acc[q][r] = 0.0f;

    for (int i0 = 0; i0 < HN; i0 += 8) {
        {
            int rr = t >> 5, cc = (t & 31) * 4;
            float4 a = *(const float4*)(Xi + (i0 + rr) * HN + cc);
            float4 b = *(const float4*)(Xi + (i0 + rr) * HN + cc + 128);
            *(float4*)&u.p1.Xs[rr][cc]       = a;
            *(float4*)&u.p1.Xs[rr][cc + 128] = b;
            u.p1.CHc[rr][t & 31] = Tdf[(i0 + rr) * HN + k0 + (t & 31)];
        }
        __syncthreads();
        #pragma unroll
        for (int ii = 0; ii < 8; ++ii) {
            float xr[8];
            *(float4*)&xr[0] = *(const float4*)&u.p1.Xs[ii][8 * ib];
            *(float4*)&xr[4] = *(const float4*)&u.p1.Xs[ii][8 * ib + 4];
            float ch[4];
            *(float4*)&ch[0] = *(const float4*)&u.p1.CHc[ii][4 * ci];
            #pragma unroll
            for (int q = 0; q < 8; ++q)
                #pragma unroll
                for (int r = 0; r < 4; ++r)
                    acc[q][r] = fmaf(ch[r], xr[q], acc[q][r]);
        }
        __syncthreads();
    }
    #pragma unroll
    for (int q = 0; q < 8; ++q)
        #pragma unroll
        for (int r = 0; r < 4; ++r)
            T1s[4 * ci + r][8 * ib + q] = acc[q][r];
    __syncthreads();

    float acc2[8][4];
    #pragma unroll
    for (int q = 0; q < 8; ++q)
        #pragma unroll
        for (int r = 0; r < 4; ++r) acc2[q][r] = 0.0f;

    for (int j0 = 0; j0 < HN; j0 += 16) {
        #pragma unroll
        for (int rep = 0; rep < 4; ++rep) {
            int idx = rep * 1024 + t * 4;
            int p = idx >> 8, c = idx & 255;
            *(float4*)&u.Bc[p][c] = *(const float4*)(Tdf + (j0 + p) * HN + c);
        }
        __syncthreads();
        #pragma unroll
        for (int p = 0; p < 16; ++p) {
            float a[4];
            #pragma unroll
            for (int r = 0; r < 4; ++r) a[r] = T1s[4 * ci + r][j0 + p];
            float b[8];
            *(float4*)&b[0] = *(const float4*)&u.Bc[p][8 * ib];
            *(float4*)&b[4] = *(const float4*)&u.Bc[p][8 * ib + 4];
            #pragma unroll
            for (int q = 0; q < 8; ++q)
                #pragma unroll
                for (int r = 0; r < 4; ++r)
                    acc2[q][r] = fmaf(a[r], b[q], acc2[q][r]);
        }
        __syncthreads();
    }

    const float mean = meanp[0];
    const float stdv = stdp[0];
    #pragma unroll
    for (int q = 0; q < 8; ++q)
        #pragma unroll
        for (int r = 0; r < 4; ++r) {
            float v = (logf(fabsf(acc2[q][r]) + 1e-13f) - mean) / stdv;
            T1s[4 * ci + r][8 * ib + q] = v;
        }
    __syncthreads();

    float* __restrict__ O = out + (size_t)img * (HN * HN) + (size_t)k0 * HN;
    #pragma unroll
    for (int rep = 0; rep < 8; ++rep) {
        int idx = rep * 1024 + t * 4;
        int row = idx >> 8, col = idx & 255;
        float4 v = make_float4(T1s[row][col], T1s[row][col + 1],
                               T1s[row][col + 2], T1s[row][col + 3]);
        *(float4*)(O + row * HN + col) = v;
    }
}

extern "C" void kernel_launch(void* const* d_in, const int* in_sizes, int n_in,
                              void* d_out, int out_size, void* d_ws, size_t ws_size,
                              hipStream_t stream) {
    const float* X     = (const float*)d_in[0];
    const float* meanp = (const float*)d_in[1];
    const float* stdp  = (const float*)d_in[2];

    float* Tdf = (float*)d_ws;                       // 256 KB basis
    const size_t T1_OFF    = 256 * 1024;
    const size_t T1_BYTES  = (size_t)NIMG * HN * HN * sizeof(float);  // 100.7MB

    basis_init<<<256, 256, 0, stream>>>(Tdf);

    if (ws_size >= T1_OFF + T1_BYTES) {
        float* T1 = (float*)((char*)d_ws + T1_OFF);
        t1_kernel<<<NIMG * 4, 256, 0, stream>>>(X, Tdf, T1);
        y_kernel <<<NIMG * 4, 256, 0, stream>>>(T1, Tdf, meanp, stdp,
                                                (float*)d_out);
    } else {
        dct2_f32<<<NIMG * 8, 256, 0, stream>>>(X, Tdf, meanp, stdp,
                                               (float*)d_out);
    }
}